// Round 1
// 359.005 us; speedup vs baseline: 1.1431x; 1.1431x over previous
//
#include <hip/hip_runtime.h>
#include <hip/hip_bf16.h>
#include <math.h>

typedef __bf16 bf16x8 __attribute__((ext_vector_type(8)));
typedef __bf16 bf16x4 __attribute__((ext_vector_type(4)));
typedef float  f32x4  __attribute__((ext_vector_type(4)));
typedef short  s16x8  __attribute__((ext_vector_type(8)));

#define N_TOK  4096
#define DMODEL 1024
#define NHEAD  4
#define DHEAD  256

__device__ __forceinline__ f32x4 mfma16x16(bf16x8 a, bf16x8 b, f32x4 c) {
    return __builtin_amdgcn_mfma_f32_16x16x32_bf16(a, b, c, 0, 0, 0);
}

// async global->LDS, 16B per lane; LDS dest = wave-uniform base + lane*16
__device__ __forceinline__ void gload_lds16(const void* gsrc, void* ldst) {
    __builtin_amdgcn_global_load_lds(
        (const __attribute__((address_space(1))) void*)gsrc,
        (__attribute__((address_space(3))) void*)ldst, 16, 0, 0);
}

// ---- GEMM: C[M,N] = ((A@B + bias) * scale, relu?, rowmask?)  (unchanged)
#define G_LDT 72  // LDS k-stride in shorts (64+8 pad); 144B rows, 16B-aligned

template<typename OutT, bool AF32>
__global__ __launch_bounds__(256, 2)
void gemm_mixed(const void* __restrict__ Av, int lda,
                const float* __restrict__ B, int ldb,
                const float* __restrict__ bias,
                OutT* __restrict__ C, int ldc,
                float scale, int relu, const float* __restrict__ rowmask)
{
    __shared__ __align__(16) short As[64 * G_LDT];
    __shared__ __align__(16) short Bs[128 * G_LDT];
    const int tid  = threadIdx.x;
    const int lane = tid & 63;
    const int wv   = tid >> 6;
    const int c16  = lane & 15;
    const int quad = lane >> 4;
    const int m0 = blockIdx.x * 64;
    const int n0 = blockIdx.y * 128;

    f32x4 acc[4][2];
    #pragma unroll
    for (int i = 0; i < 4; ++i)
        #pragma unroll
        for (int j = 0; j < 2; ++j)
            acc[i][j] = (f32x4){0.f, 0.f, 0.f, 0.f};

    const int bn = tid & 127;
    const int bh = tid >> 7;

    for (int k0 = 0; k0 < 1024; k0 += 64) {
        if (AF32) {
            const float* A = (const float*)Av;
            #pragma unroll
            for (int r = 0; r < 4; ++r) {
                int i = tid + r * 256;
                int m = i >> 4, c = i & 15;
                f32x4 t = *(const f32x4*)(A + (size_t)(m0 + m) * lda + k0 + c * 4);
                bf16x4 b;
                #pragma unroll
                for (int j = 0; j < 4; ++j) b[j] = (__bf16)t[j];
                *(bf16x4*)(&As[m * G_LDT + c * 4]) = b;
            }
        } else {
            const __bf16* A = (const __bf16*)Av;
            #pragma unroll
            for (int r = 0; r < 2; ++r) {
                int i = tid + r * 256;
                int m = i >> 3, c = i & 7;
                *(s16x8*)(&As[m * G_LDT + c * 8]) =
                    *(const s16x8*)(A + (size_t)(m0 + m) * lda + k0 + c * 8);
            }
        }
        {
            const float* bp = B + (size_t)(k0 + bh * 32) * ldb + n0 + bn;
            #pragma unroll
            for (int g = 0; g < 4; ++g) {
                bf16x8 t;
                #pragma unroll
                for (int j = 0; j < 8; ++j) t[j] = (__bf16)bp[(size_t)(g * 8 + j) * ldb];
                *(bf16x8*)(&Bs[bn * G_LDT + bh * 32 + g * 8]) = t;
            }
        }
        __syncthreads();
        #pragma unroll
        for (int ks = 0; ks < 2; ++ks) {
            bf16x8 af[4], bfr[2];
            #pragma unroll
            for (int t = 0; t < 4; ++t)
                af[t] = *(const bf16x8*)(&As[(t * 16 + c16) * G_LDT + ks * 32 + quad * 8]);
            #pragma unroll
            for (int t = 0; t < 2; ++t)
                bfr[t] = *(const bf16x8*)(&Bs[(wv * 32 + t * 16 + c16) * G_LDT + ks * 32 + quad * 8]);
            #pragma unroll
            for (int tm = 0; tm < 4; ++tm)
                #pragma unroll
                for (int tn = 0; tn < 2; ++tn)
                    acc[tm][tn] = mfma16x16(af[tm], bfr[tn], acc[tm][tn]);
        }
        __syncthreads();
    }

    #pragma unroll
    for (int tm = 0; tm < 4; ++tm) {
        #pragma unroll
        for (int r = 0; r < 4; ++r) {
            int row = m0 + tm * 16 + quad * 4 + r;
            float mk = rowmask ? rowmask[row] : 1.0f;
            #pragma unroll
            for (int tn = 0; tn < 2; ++tn) {
                int col = n0 + wv * 32 + tn * 16 + c16;
                float val = (acc[tm][tn][r] + bias[col]) * scale;
                if (relu) val = fmaxf(val, 0.0f);
                val *= mk;
                C[(size_t)row * ldc + col] = (OutT)val;
            }
        }
    }
}

// ---- scores -> mask (unchanged)
__global__ void score_mask_kernel(const __bf16* __restrict__ h,
                                  const float* __restrict__ w2,
                                  const float* __restrict__ b2,
                                  float* __restrict__ maskf)
{
    int lane = threadIdx.x & 63;
    int tok  = blockIdx.x * 4 + (threadIdx.x >> 6);
    const __bf16* hr = h + (size_t)tok * 256;
    float s = 0.f;
    #pragma unroll
    for (int j = 0; j < 4; ++j) {
        int c = j * 64 + lane;
        s += (float)hr[c] * w2[c];
    }
    #pragma unroll
    for (int o = 1; o < 64; o <<= 1) s += __shfl_xor(s, o);
    if (lane == 0) {
        float x = s + b2[0];
        maskf[tok] = (x > -1.7346010553881064f) ? 1.0f : 0.0f;
    }
}

// ---- transpose vp [4096][1024] -> vpT [1024][4096] (bf16). 64x64 tiles.
// Coalesced both sides; scalar LDS scatter on the write side (tiny kernel).
__global__ __launch_bounds__(256)
void transpose_kernel(const __bf16* __restrict__ in, __bf16* __restrict__ out)
{
    __shared__ __align__(16) short tile[64 * 72];  // [col][tok], 144B rows (16B-aligned)
    const int tid = threadIdx.x;
    const int t0 = blockIdx.x * 64;
    const int c0 = blockIdx.y * 64;
    #pragma unroll
    for (int it = 0; it < 2; ++it) {
        int i = tid + it * 256;
        int tok = i >> 3, ch = i & 7;
        s16x8 v = *(const s16x8*)((const short*)in + (size_t)(t0 + tok) * DMODEL + c0 + ch * 8);
        #pragma unroll
        for (int j = 0; j < 8; ++j)
            tile[(ch * 8 + j) * 72 + tok] = v[j];
    }
    __syncthreads();
    #pragma unroll
    for (int it = 0; it < 2; ++it) {
        int i = tid + it * 256;
        int col = i >> 3, och = i & 7;
        s16x8 v = *(const s16x8*)(&tile[col * 72 + och * 8]);
        *(s16x8*)((short*)out + (size_t)(c0 + col) * N_TOK + t0 + och * 8) = v;
    }
}

// ---- flash attention, key-masked, fixed-max softmax, split over key halves.
// LDS layouts are LINEAR rows with XOR chunk swizzle (16B chunk c of row r
// stored at chunk c^(r&7)); staged via global_load_lds with pre-swizzled
// per-lane GLOBAL source (rule #21: source perm == read perm, both involution).
//   Ks [64 key][256 dh]   rows 512B (32 chunks)
//   Vs [256 dh][64 key]   rows 128B (8 chunks)   <- from pre-transposed vpT
//   Ps [16 qrow][64 key]  rows 128B (8 chunks), per-wave
template<bool SPLIT>
__global__ __launch_bounds__(256, 2)
void attn_kernel(const __bf16* __restrict__ qp, const __bf16* __restrict__ kp,
                 const __bf16* __restrict__ vpT, const float* __restrict__ maskf,
                 __bf16* __restrict__ O0, __bf16* __restrict__ O1,
                 float* __restrict__ lbuf)
{
    __shared__ __align__(16) short Ks[64 * 256];    // 32 KB
    __shared__ __align__(16) short Vs[256 * 64];    // 32 KB
    __shared__ __align__(16) short PsA[4 * 16 * 64]; // 8 KB

    const int tid  = threadIdx.x;
    const int lane = tid & 63;
    const int wv   = tid >> 6;
    const int c16  = lane & 15;
    const int quad = lane >> 4;
    const int swz  = c16 & 7;            // (row&7) for all fragment reads
    const int head = blockIdx.y;
    const int ksp  = SPLIT ? blockIdx.z : 0;
    const int kbase = ksp * (SPLIT ? 2048 : 0);
    const int kend  = kbase + (SPLIT ? 2048 : 4096);
    const int q0   = blockIdx.x * 64 + wv * 16;
    short* Ps = PsA + wv * 16 * 64;
    __bf16* Ob = (SPLIT && ksp == 1) ? O1 : O0;

    // Q fragments (A-layout: m = lane&15, k = quad*8+j); qp pre-scaled by 1/16
    bf16x8 qf[8];
    #pragma unroll
    for (int c = 0; c < 8; ++c)
        qf[c] = *(const bf16x8*)(qp + (size_t)(q0 + c16) * DMODEL + head * DHEAD + c * 32 + quad * 8);

    f32x4 o[16];
    #pragma unroll
    for (int t = 0; t < 16; ++t) o[t] = (f32x4){0.f, 0.f, 0.f, 0.f};
    float psum[4] = {0.f, 0.f, 0.f, 0.f};

    // staging lane geometry (wave w stages K rows [16w,16w+16), V rows [64w,64w+64))
    const int kRow0 = wv * 16 + (lane >> 5);        // + 2g
    const int kCh   = lane & 31;
    const int vRow0 = wv * 64 + (lane >> 3);        // + 8g
    const int vCh   = (lane & 7) ^ ((lane >> 3) & 7); // row&7 == (lane>>3)&7 (g*8,w*64 == 0 mod 8)

    #pragma unroll 1
    for (int n0 = kbase; n0 < kend; n0 += 64) {
        // K tile: 8 x global_load_lds (2 rows / instr), source pre-swizzled
        #pragma unroll
        for (int g = 0; g < 8; ++g) {
            int key = kRow0 + g * 2;
            int c   = kCh ^ (key & 7);
            const char* src = (const char*)(kp + (size_t)(n0 + key) * DMODEL + head * DHEAD) + c * 16;
            gload_lds16(src, (char*)Ks + (wv * 16 + g * 2) * 512);
        }
        // V tile: 8 x global_load_lds (8 rows / instr), from vpT rows (contiguous tokens)
        #pragma unroll
        for (int g = 0; g < 8; ++g) {
            int row = vRow0 + g * 8;
            const char* src = (const char*)(vpT + (size_t)(head * DHEAD + row) * N_TOK + n0) + vCh * 16;
            gload_lds16(src, (char*)Vs + (wv * 64 + g * 8) * 128);
        }
        __syncthreads();   // drains vmcnt -> LDS tiles complete

        // S = Q K^T
        f32x4 s[4];
        #pragma unroll
        for (int kt = 0; kt < 4; ++kt) s[kt] = (f32x4){0.f, 0.f, 0.f, 0.f};
        __builtin_amdgcn_s_setprio(1);
        #pragma unroll
        for (int c = 0; c < 8; ++c)
            #pragma unroll
            for (int kt = 0; kt < 4; ++kt) {
                bf16x8 bfr = *(const bf16x8*)(&Ks[(kt * 16 + c16) * 256 + (((c * 4 + quad) ^ swz) << 3)]);
                s[kt] = mfma16x16(qf[c], bfr, s[kt]);
            }
        __builtin_amdgcn_s_setprio(0);

        // p = exp(s + maskbias); accumulate denominator; store P swizzled
        #pragma unroll
        for (int kt = 0; kt < 4; ++kt) {
            float biasv = (maskf[n0 + kt * 16 + c16] - 1.0f) * 1e9f;  // 0 or -1e9
            #pragma unroll
            for (int r = 0; r < 4; ++r) {
                float p = __expf(s[kt][r] + biasv);
                psum[r] += p;
                int qrow = quad * 4 + r;
                int ch = (kt * 2 + (c16 >> 3)) ^ (qrow & 7);   // (key>>3) ^ (qrow&7)
                *(__bf16*)&Ps[qrow * 64 + ch * 8 + swz] = (__bf16)p;  // key&7 == c16&7
            }
        }

        __builtin_amdgcn_s_waitcnt(0xc07f);  // lgkmcnt(0): own-wave Ps writes visible

        // O += P @ V
        __builtin_amdgcn_s_setprio(1);
        #pragma unroll
        for (int kstep = 0; kstep < 2; ++kstep) {
            bf16x8 pf = *(const bf16x8*)(&Ps[c16 * 64 + (((kstep * 4 + quad) ^ swz) << 3)]);
            #pragma unroll
            for (int t = 0; t < 16; ++t) {
                bf16x8 vf = *(const bf16x8*)(&Vs[(t * 16 + c16) * 64 + (((kstep * 4 + quad) ^ swz) << 3)]);
                o[t] = mfma16x16(pf, vf, o[t]);
            }
        }
        __builtin_amdgcn_s_setprio(0);
        __syncthreads();
    }

    // end-of-kernel denominator reduce across the 16 lanes of each quad-row
    float inv[4];
    #pragma unroll
    for (int r = 0; r < 4; ++r) {
        float t = psum[r];
        t += __shfl_xor(t, 1);
        t += __shfl_xor(t, 2);
        t += __shfl_xor(t, 4);
        t += __shfl_xor(t, 8);
        if (SPLIT && c16 == 0)
            lbuf[(size_t)(ksp * NHEAD + head) * N_TOK + q0 + quad * 4 + r] = t;
        inv[r] = 1.0f / t;
    }
    #pragma unroll
    for (int t = 0; t < 16; ++t)
        #pragma unroll
        for (int r = 0; r < 4; ++r) {
            float val = o[t][r] * inv[r];
            Ob[(size_t)(q0 + quad * 4 + r) * DMODEL + head * DHEAD + t * 16 + c16] = (__bf16)val;
        }
}

// ---- combine: ctx = (l0*O0 + l1*O1) / (l0+l1); exact (shared m=0)
__global__ void combine_kernel(const __bf16* __restrict__ O0,
                               const __bf16* __restrict__ O1,
                               const float* __restrict__ lbuf,
                               __bf16* __restrict__ out)
{
    int idx  = blockIdx.x * 256 + threadIdx.x;   // one per 8 elements
    int tok  = idx >> 7;
    int g    = idx & 127;
    int head = g >> 5;
    float a = lbuf[(size_t)head * N_TOK + tok];
    float b = lbuf[(size_t)(NHEAD + head) * N_TOK + tok];
    float w0 = a / (a + b);
    float w1 = 1.0f - w0;
    size_t off = (size_t)tok * DMODEL + g * 8;
    bf16x8 x = *(const bf16x8*)(O0 + off);
    bf16x8 y = *(const bf16x8*)(O1 + off);
    bf16x8 z;
    #pragma unroll
    for (int j = 0; j < 8; ++j) z[j] = (__bf16)(w0 * (float)x[j] + w1 * (float)y[j]);
    *(bf16x8*)(out + off) = z;
}

extern "C" void kernel_launch(void* const* d_in, const int* in_sizes, int n_in,
                              void* d_out, int out_size, void* d_ws, size_t ws_size,
                              hipStream_t stream)
{
    (void)in_sizes; (void)n_in; (void)out_size;
    const float* q  = (const float*)d_in[0];
    const float* k  = (const float*)d_in[1];
    const float* v  = (const float*)d_in[2];
    const float* w1 = (const float*)d_in[3];
    const float* b1 = (const float*)d_in[4];
    const float* w2 = (const float*)d_in[5];
    const float* b2 = (const float*)d_in[6];
    const float* wq = (const float*)d_in[7];
    const float* bq = (const float*)d_in[8];
    const float* wk = (const float*)d_in[9];
    const float* bk = (const float*)d_in[10];
    const float* wvw = (const float*)d_in[11];
    const float* bv = (const float*)d_in[12];
    const float* wo = (const float*)d_in[13];
    const float* bo = (const float*)d_in[14];

    if (ws_size < 35667968u) return;  // proven floor (R2 passed with this layout)

    char* ws = (char*)d_ws;
    float*  maskf = (float*)ws;                       // 16 KB
    __bf16* hbuf  = (__bf16*)(ws + 16384);            // 4096x256  = 2 MB
    __bf16* qp    = (__bf16*)(ws + 16384 + 2097152);  // 4096x1024 = 8 MB each
    __bf16* kpb   = qp  + 4194304;
    __bf16* vpb   = kpb + 4194304;
    __bf16* ctx   = vpb + 4194304;                    // also O0 in split path
    // split-path extras appended past the R2 layout (35,667,968 B)
    __bf16* O1    = (__bf16*)(ws + 35667968u);        // 8 MB
    float*  lbuf  = (float*)(ws + 35667968u + 8388608u);  // 2*4*4096*4 = 128 KB
    const bool split = ws_size >= 35667968u + 8388608u + 131072u;

    // vpT [1024][4096] lives in d_out (16 MB): dead until the final out-proj
    // GEMM overwrites it; stream-ordered so no overlap.
    __bf16* vpT = (__bf16*)d_out;

    gemm_mixed<__bf16, true><<<dim3(64, 2), 256, 0, stream>>>(q, 1024, w1, 256, b1, hbuf, 256, 1.0f, 1, nullptr);
    score_mask_kernel<<<1024, 256, 0, stream>>>(hbuf, w2, b2, maskf);
    gemm_mixed<__bf16, true><<<dim3(64, 8), 256, 0, stream>>>(q, 1024, wq, 1024, bq, qp, 1024, 0.0625f, 0, nullptr);
    gemm_mixed<__bf16, true><<<dim3(64, 8), 256, 0, stream>>>(k, 1024, wk, 1024, bk, kpb, 1024, 1.0f, 0, nullptr);
    gemm_mixed<__bf16, true><<<dim3(64, 8), 256, 0, stream>>>(v, 1024, wvw, 1024, bv, vpb, 1024, 1.0f, 0, nullptr);
    transpose_kernel<<<dim3(64, 16), 256, 0, stream>>>(vpb, vpT);

    if (split) {
        attn_kernel<true><<<dim3(64, 4, 2), 256, 0, stream>>>(qp, kpb, vpT, maskf, ctx, O1, lbuf);
        combine_kernel<<<2048, 256, 0, stream>>>(ctx, O1, lbuf, ctx);
    } else {
        attn_kernel<false><<<dim3(64, 4, 1), 256, 0, stream>>>(qp, kpb, vpT, maskf, ctx, nullptr, nullptr);
    }

    gemm_mixed<float, false><<<dim3(64, 8), 256, 0, stream>>>(ctx, 1024, wo, 1024, bo, (float*)d_out, 1024, 1.0f, 0, maskf);
}